// Round 1
// baseline (79.205 us; speedup 1.0000x reference)
//
#include <hip/hip_runtime.h>

namespace {
constexpr int B   = 8;
constexpr int TQ  = 256;
constexpr int TK  = 256;
constexpr int DQK = 512;
constexpr int DV  = 512;
constexpr int H   = 256;
constexpr float C2LOG2E = 2.8853900817779268f; // 2*log2(e)
constexpr float LOG2E   = 1.4426950408889634f;
} // namespace

// Fused projections:
//  z==0: qpc[b*TQ+q][h]  = (queries @ Wq)[row][h] * 2log2e
//  z==1: kpcT[b][h][k]   = (keys    @ Wk)[row][h] * 2log2e   (transposed store)
__global__ __launch_bounds__(256)
void proj_kernel(const float* __restrict__ Q, const float* __restrict__ Kin,
                 const float* __restrict__ Wq, const float* __restrict__ Wk,
                 float* __restrict__ qpc, float* __restrict__ kpcT)
{
    constexpr int BM = 64, BN = 32, BK = 16;
    __shared__ float As[BK][BM];   // A tile stored transposed
    __shared__ float Bs[BK][BN];

    const bool kside = (blockIdx.z == 1);
    const float* A = kside ? Kin : Q;
    const float* W = kside ? Wk  : Wq;
    const int m0 = blockIdx.x * BM;
    const int n0 = blockIdx.y * BN;
    const int tid = threadIdx.x;
    const int tx = tid & 15;        // n dir (16 threads * 2 cols)
    const int ty = tid >> 4;        // m dir (16 threads * 4 rows)
    const int ar = tid >> 2, ac4 = (tid & 3) * 4;
    const int br = tid >> 4, bc2 = (tid & 15) * 2;

    float acc[4][2] = {};
    for (int k0 = 0; k0 < DQK; k0 += BK) {
        float4 av = *(const float4*)(A + (m0 + ar) * DQK + k0 + ac4);
        float2 bv = *(const float2*)(W + (k0 + br) * H + n0 + bc2);
        __syncthreads();  // protect previous iteration's LDS reads
        As[ac4 + 0][ar] = av.x;
        As[ac4 + 1][ar] = av.y;
        As[ac4 + 2][ar] = av.z;
        As[ac4 + 3][ar] = av.w;
        *(float2*)&Bs[br][bc2] = bv;
        __syncthreads();
        #pragma unroll
        for (int kk = 0; kk < BK; ++kk) {
            float4 a = *(const float4*)&As[kk][ty * 4];
            float2 b = *(const float2*)&Bs[kk][tx * 2];
            acc[0][0] = fmaf(a.x, b.x, acc[0][0]);
            acc[0][1] = fmaf(a.x, b.y, acc[0][1]);
            acc[1][0] = fmaf(a.y, b.x, acc[1][0]);
            acc[1][1] = fmaf(a.y, b.y, acc[1][1]);
            acc[2][0] = fmaf(a.z, b.x, acc[2][0]);
            acc[2][1] = fmaf(a.z, b.y, acc[2][1]);
            acc[3][0] = fmaf(a.w, b.x, acc[3][0]);
            acc[3][1] = fmaf(a.w, b.y, acc[3][1]);
        }
    }

    if (!kside) {
        #pragma unroll
        for (int i = 0; i < 4; ++i) {
            float2 v = make_float2(acc[i][0] * C2LOG2E, acc[i][1] * C2LOG2E);
            *(float2*)(qpc + (m0 + ty * 4 + i) * H + n0 + tx * 2) = v;
        }
    } else {
        #pragma unroll
        for (int j = 0; j < 2; ++j) {
            const int col = n0 + tx * 2 + j;
            const int row = m0 + ty * 4;       // row = b*256 + k
            const int bb  = row >> 8;
            float4 v = make_float4(acc[0][j] * C2LOG2E, acc[1][j] * C2LOG2E,
                                   acc[2][j] * C2LOG2E, acc[3][j] * C2LOG2E);
            *(float4*)(kpcT + (bb * H + col) * TK + (row & 255)) = v;
        }
    }
}

// Fused scores + softmax + PV. One block handles (b, q0..q0+3); thread k owns
// score column k. logits = -2 * sum_h wv[h] * rcp(exp2(qpc+kpc) + 1)
__global__ __launch_bounds__(256)
void attn_kernel(const float* __restrict__ qpc, const float* __restrict__ kpcT,
                 const float* __restrict__ wv, const float* __restrict__ values,
                 float* __restrict__ out)
{
    constexpr int QB = 4;
    __shared__ float qlds[QB][H];
    __shared__ float wlds[H];
    __shared__ float elds[QB][TK];
    __shared__ float rowsum[QB];

    const int b   = blockIdx.x / (TQ / QB);
    const int q0  = (blockIdx.x % (TQ / QB)) * QB;
    const int tid = threadIdx.x;

    #pragma unroll
    for (int i = 0; i < QB; ++i)
        qlds[i][tid] = qpc[(b * TQ + q0 + i) * H + tid];
    wlds[tid] = wv[tid];
    __syncthreads();

    const float* kcol = kpcT + b * H * TK + tid;
    float acc[QB] = {};
    #pragma unroll 4
    for (int h = 0; h < H; ++h) {
        float kv = kcol[h * TK];
        float w  = wlds[h];
        #pragma unroll
        for (int q = 0; q < QB; ++q) {
            float e = __builtin_amdgcn_exp2f(qlds[q][h] + kv);
            float r = __builtin_amdgcn_rcpf(e + 1.0f);
            acc[q] = fmaf(w, r, acc[q]);
        }
    }

    #pragma unroll
    for (int q = 0; q < QB; ++q) elds[q][tid] = -2.0f * acc[q];
    __syncthreads();

    // per-row softmax: wave w handles row w (4 waves == QB)
    {
        const int wave = tid >> 6, lane = tid & 63;
        const int q = wave;
        float4 v = *(const float4*)&elds[q][lane * 4];
        float m = fmaxf(fmaxf(v.x, v.y), fmaxf(v.z, v.w));
        #pragma unroll
        for (int off = 1; off < 64; off <<= 1)
            m = fmaxf(m, __shfl_xor(m, off));
        float e0 = __builtin_amdgcn_exp2f((v.x - m) * LOG2E);
        float e1 = __builtin_amdgcn_exp2f((v.y - m) * LOG2E);
        float e2 = __builtin_amdgcn_exp2f((v.z - m) * LOG2E);
        float e3 = __builtin_amdgcn_exp2f((v.w - m) * LOG2E);
        float s = (e0 + e1) + (e2 + e3);
        #pragma unroll
        for (int off = 1; off < 64; off <<= 1)
            s += __shfl_xor(s, off);
        *(float4*)&elds[q][lane * 4] = make_float4(e0, e1, e2, e3);
        if (lane == 0) rowsum[q] = s;
    }
    __syncthreads();

    // PV: thread owns output cols tid and tid+256 for all QB rows
    float o[QB][2] = {};
    const float* vb = values + b * TK * DV;
    for (int k = 0; k < TK; ++k) {
        float v0 = vb[k * DV + tid];
        float v1 = vb[k * DV + tid + 256];
        #pragma unroll
        for (int q = 0; q < QB; ++q) {
            float p = elds[q][k];
            o[q][0] = fmaf(p, v0, o[q][0]);
            o[q][1] = fmaf(p, v1, o[q][1]);
        }
    }
    #pragma unroll
    for (int q = 0; q < QB; ++q) {
        float inv = __builtin_amdgcn_rcpf(rowsum[q]);
        float* op = out + (b * TQ + q0 + q) * DV;
        op[tid]       = o[q][0] * inv;
        op[tid + 256] = o[q][1] * inv;
    }
}

extern "C" void kernel_launch(void* const* d_in, const int* in_sizes, int n_in,
                              void* d_out, int out_size, void* d_ws, size_t ws_size,
                              hipStream_t stream)
{
    const float* queries = (const float*)d_in[0];
    const float* keys    = (const float*)d_in[1];
    const float* values  = (const float*)d_in[2];
    const float* Wq      = (const float*)d_in[3];
    const float* Wk      = (const float*)d_in[4];
    const float* wv      = (const float*)d_in[5];
    float* out  = (float*)d_out;
    float* qpc  = (float*)d_ws;                  // (B*TQ, H)   2 MB
    float* kpcT = qpc + B * TQ * H;              // (B, H, TK)  2 MB

    dim3 gproj(B * TQ / 64, H / 32, 2);
    proj_kernel<<<gproj, 256, 0, stream>>>(queries, keys, Wq, Wk, qpc, kpcT);
    attn_kernel<<<B * (TQ / 4), 256, 0, stream>>>(qpc, kpcT, wv, values, out);
}

// Round 3
// 70.996 us; speedup vs baseline: 1.1156x; 1.1156x over previous
//
#include <hip/hip_runtime.h>

namespace {
constexpr int B   = 8;
constexpr int TQ  = 256;
constexpr int TK  = 256;
constexpr int DQK = 512;
constexpr int DV  = 512;
constexpr int H   = 256;
constexpr int QB  = 4;
constexpr float C2LOG2E = 2.8853900817779268f; // 2*log2(e)
constexpr float LOG2E   = 1.4426950408889634f;
} // namespace

// Fused projections:
//  z==0: qpc[b*TQ+q][h]  = (queries @ Wq)[row][h] * 2log2e
//  z==1: kpcT[b][h][k]   = (keys    @ Wk)[row][h] * 2log2e   (transposed store)
__global__ __launch_bounds__(256)
void proj_kernel(const float* __restrict__ Q, const float* __restrict__ Kin,
                 const float* __restrict__ Wq, const float* __restrict__ Wk,
                 float* __restrict__ qpc, float* __restrict__ kpcT)
{
    constexpr int BM = 64, BN = 32, BK = 16;
    __shared__ float As[BK][BM];   // A tile stored transposed
    __shared__ float Bs[BK][BN];

    const bool kside = (blockIdx.z == 1);
    const float* A = kside ? Kin : Q;
    const float* W = kside ? Wk  : Wq;
    const int m0 = blockIdx.x * BM;
    const int n0 = blockIdx.y * BN;
    const int tid = threadIdx.x;
    const int tx = tid & 15;        // n dir (16 threads * 2 cols)
    const int ty = tid >> 4;        // m dir (16 threads * 4 rows)
    const int ar = tid >> 2, ac4 = (tid & 3) * 4;
    const int br = tid >> 4, bc2 = (tid & 15) * 2;

    float acc[4][2] = {};
    for (int k0 = 0; k0 < DQK; k0 += BK) {
        float4 av = *(const float4*)(A + (m0 + ar) * DQK + k0 + ac4);
        float2 bv = *(const float2*)(W + (k0 + br) * H + n0 + bc2);
        __syncthreads();  // protect previous iteration's LDS reads
        As[ac4 + 0][ar] = av.x;
        As[ac4 + 1][ar] = av.y;
        As[ac4 + 2][ar] = av.z;
        As[ac4 + 3][ar] = av.w;
        *(float2*)&Bs[br][bc2] = bv;
        __syncthreads();
        #pragma unroll
        for (int kk = 0; kk < BK; ++kk) {
            float4 a = *(const float4*)&As[kk][ty * 4];
            float2 b = *(const float2*)&Bs[kk][tx * 2];
            acc[0][0] = fmaf(a.x, b.x, acc[0][0]);
            acc[0][1] = fmaf(a.x, b.y, acc[0][1]);
            acc[1][0] = fmaf(a.y, b.x, acc[1][0]);
            acc[1][1] = fmaf(a.y, b.y, acc[1][1]);
            acc[2][0] = fmaf(a.z, b.x, acc[2][0]);
            acc[2][1] = fmaf(a.z, b.y, acc[2][1]);
            acc[3][0] = fmaf(a.w, b.x, acc[3][0]);
            acc[3][1] = fmaf(a.w, b.y, acc[3][1]);
        }
    }

    if (!kside) {
        #pragma unroll
        for (int i = 0; i < 4; ++i) {
            float2 v = make_float2(acc[i][0] * C2LOG2E, acc[i][1] * C2LOG2E);
            *(float2*)(qpc + (m0 + ty * 4 + i) * H + n0 + tx * 2) = v;
        }
    } else {
        #pragma unroll
        for (int j = 0; j < 2; ++j) {
            const int col = n0 + tx * 2 + j;
            const int row = m0 + ty * 4;       // row = b*256 + k
            const int bb  = row >> 8;
            float4 v = make_float4(acc[0][j] * C2LOG2E, acc[1][j] * C2LOG2E,
                                   acc[2][j] * C2LOG2E, acc[3][j] * C2LOG2E);
            *(float4*)(kpcT + (bb * H + col) * TK + (row & 255)) = v;
        }
    }
}

// Fused scores + softmax + PV. One block = (b, q0..q0+3), 512 threads.
// Thread (k = tid&255, half = tid>>8). Score phase: half splits H.
// PV phase: half splits K. LDS partial reduction for both.
// logits = -2 * sum_h wv[h] * rcp(exp2(qpc+kpc) + 1)   (constant term cancels)
__global__ __launch_bounds__(512)
void attn_kernel(const float* __restrict__ qpc, const float* __restrict__ kpcT,
                 const float* __restrict__ wv, const float* __restrict__ values,
                 float* __restrict__ out)
{
    __shared__ float qlds[QB][H];        // 4 KB
    __shared__ float wlds[H];            // 1 KB
    __shared__ float elds[QB][TK];       // 4 KB
    __shared__ float accbuf[2][QB][DV];  // 16 KB (score phase uses [..][..][0:TK])
    __shared__ float rowsum[QB];

    const int b    = blockIdx.x / (TQ / QB);
    const int q0   = (blockIdx.x % (TQ / QB)) * QB;
    const int tid  = threadIdx.x;
    const int k    = tid & 255;
    const int half = tid >> 8;

    for (int i = tid; i < QB * H; i += 512)
        qlds[i >> 8][i & 255] = qpc[(b * TQ + q0 + (i >> 8)) * H + (i & 255)];
    if (tid < H) wlds[tid] = wv[tid];
    __syncthreads();

    // ---- score phase: half h-range per thread-half ----
    const float* kcol = kpcT + b * H * TK + k;
    float acc[QB] = {};
    const int h0base = half * (H / 2);
    for (int h0 = h0base; h0 < h0base + H / 2; h0 += 4) {
        float4 w4 = *(const float4*)&wlds[h0];
        float4 q4[QB];
        #pragma unroll
        for (int q = 0; q < QB; ++q) q4[q] = *(const float4*)&qlds[q][h0];
        float kv0 = kcol[(h0 + 0) * TK];
        float kv1 = kcol[(h0 + 1) * TK];
        float kv2 = kcol[(h0 + 2) * TK];
        float kv3 = kcol[(h0 + 3) * TK];
        #pragma unroll
        for (int q = 0; q < QB; ++q) {
            acc[q] = fmaf(w4.x, __builtin_amdgcn_rcpf(__builtin_amdgcn_exp2f(q4[q].x + kv0) + 1.0f), acc[q]);
            acc[q] = fmaf(w4.y, __builtin_amdgcn_rcpf(__builtin_amdgcn_exp2f(q4[q].y + kv1) + 1.0f), acc[q]);
            acc[q] = fmaf(w4.z, __builtin_amdgcn_rcpf(__builtin_amdgcn_exp2f(q4[q].z + kv2) + 1.0f), acc[q]);
            acc[q] = fmaf(w4.w, __builtin_amdgcn_rcpf(__builtin_amdgcn_exp2f(q4[q].w + kv3) + 1.0f), acc[q]);
        }
    }
    #pragma unroll
    for (int q = 0; q < QB; ++q) accbuf[half][q][k] = acc[q];
    __syncthreads();

    // ---- combine halves -> logits ----
    for (int i = tid; i < QB * TK; i += 512) {
        const int q = i >> 8, kk = i & 255;
        elds[q][kk] = -2.0f * (accbuf[0][q][kk] + accbuf[1][q][kk]);
    }
    __syncthreads();

    // ---- softmax: wave w (of first 4) handles row w ----
    if (tid < 256) {
        const int q = tid >> 6, lane = tid & 63;
        float4 v = *(const float4*)&elds[q][lane * 4];
        float m = fmaxf(fmaxf(v.x, v.y), fmaxf(v.z, v.w));
        #pragma unroll
        for (int off = 1; off < 64; off <<= 1)
            m = fmaxf(m, __shfl_xor(m, off));
        float e0 = __builtin_amdgcn_exp2f((v.x - m) * LOG2E);
        float e1 = __builtin_amdgcn_exp2f((v.y - m) * LOG2E);
        float e2 = __builtin_amdgcn_exp2f((v.z - m) * LOG2E);
        float e3 = __builtin_amdgcn_exp2f((v.w - m) * LOG2E);
        float s = (e0 + e1) + (e2 + e3);
        #pragma unroll
        for (int off = 1; off < 64; off <<= 1)
            s += __shfl_xor(s, off);
        *(float4*)&elds[q][lane * 4] = make_float4(e0, e1, e2, e3);
        if (lane == 0) rowsum[q] = s;
    }
    __syncthreads();

    // ---- PV: half k-range per thread-half; thread owns cols k, k+256 ----
    float o[QB][2] = {};
    const float* vb = values + b * TK * DV;
    const int kbeg = half * (TK / 2);
    for (int kk = kbeg; kk < kbeg + TK / 2; ++kk) {
        float v0 = vb[kk * DV + k];
        float v1 = vb[kk * DV + k + 256];
        #pragma unroll
        for (int q = 0; q < QB; ++q) {
            float p = elds[q][kk];
            o[q][0] = fmaf(p, v0, o[q][0]);
            o[q][1] = fmaf(p, v1, o[q][1]);
        }
    }
    #pragma unroll
    for (int q = 0; q < QB; ++q) {
        accbuf[half][q][k]       = o[q][0];
        accbuf[half][q][k + 256] = o[q][1];
    }
    __syncthreads();

    for (int i = tid; i < QB * DV; i += 512) {
        const int q = i >> 9, c = i & 511;
        float val = (accbuf[0][q][c] + accbuf[1][q][c]) *
                    __builtin_amdgcn_rcpf(rowsum[q]);
        out[(b * TQ + q0 + q) * DV + c] = val;
    }
}

extern "C" void kernel_launch(void* const* d_in, const int* in_sizes, int n_in,
                              void* d_out, int out_size, void* d_ws, size_t ws_size,
                              hipStream_t stream)
{
    const float* queries = (const float*)d_in[0];
    const float* keys    = (const float*)d_in[1];
    const float* values  = (const float*)d_in[2];
    const float* Wq      = (const float*)d_in[3];
    const float* Wk      = (const float*)d_in[4];
    const float* wv      = (const float*)d_in[5];
    float* out  = (float*)d_out;
    float* qpc  = (float*)d_ws;                  // (B*TQ, H)   2 MB
    float* kpcT = qpc + B * TQ * H;              // (B, H, TK)  2 MB

    dim3 gproj(B * TQ / 64, H / 32, 2);
    proj_kernel<<<gproj, 256, 0, stream>>>(queries, keys, Wq, Wk, qpc, kpcT);
    attn_kernel<<<B * (TQ / QB), 512, 0, stream>>>(qpc, kpcT, wv, values, out);
}